// Round 1
// baseline (127.949 us; speedup 1.0000x reference)
//
#include <hip/hip_runtime.h>
#include <math.h>

#define HOP     200
#define NB      32
#define TLEN    480000
#define NROWS   2440        // padded pg rows per batch; row s <-> segment g = s-3

#define NSEG1   40          // segments per block, kernel 1 (partials)
#define NBLK1   61          // ceil(NROWS / NSEG1)

#define SEGO    40          // output segments per block, kernel 2 (synth)
#define NT2     60          // 2400 / SEGO

// fallback single-kernel tile params (original validated kernel)
#define SEG     60
#define NTILE   (TLEN / HOP / SEG)     // 40
#define NSEGP   (SEG + 6)              // 66

#define DLT  0.00785398163397448f      // 2*pi/800
// cos/sin of k*DLT, k=1..3 (within-float4 angle stepping)
#define C1K  0.99996915760f
#define S1K  0.00785390090f
#define C2K  0.99987663248f
#define S2K  0.01570731731f
#define C3K  0.99972243010f
#define S3K  0.02355976470f
// rotation by 40*DLT = pi/10 (between a thread's successive float4s)
#define C40  0.95105651629515f
#define S40  0.30901699437495f

typedef float floatx4 __attribute__((ext_vector_type(4)));

// ---------------------------------------------------------------------------
// Kernel 1: x -> per-segment basis partials pg[b][row][6]
//   row s covers segment g = s-3 (g in [-3, NROWS-4]); rows beyond g=2401 are
//   computed (cheap, edge-clamped) but never read by kernel 2.
//   Pure read stream, zero halo: each x sample is touched exactly once.
// ---------------------------------------------------------------------------
__global__ __launch_bounds__(256) void stft_part(const float* __restrict__ x,
                                                 float* __restrict__ pg) {
    __shared__ float part[NSEG1][10][6];   // 9.6 KB
    const int b  = blockIdx.y;
    const int s0 = blockIdx.x * NSEG1;
    const float* xb = x + (size_t)b * TLEN;

    for (int u = threadIdx.x; u < NSEG1 * 10; u += 256) {
        const int s = u / 10;
        const int k = u - 10 * s;
        const int g = s0 + s - 3;
        const int gm = (g + 4) & 3;         // t mod 800 phase
        float c0, sn0;
        __sincosf((float)(gm * 200 + 4 * k) * DLT, &sn0, &c0);
        float p1e = 0.f, p1o = 0.f, pce = 0.f, pco = 0.f, pse = 0.f, pso = 0.f;
        const bool inb = (g >= 0) && (g <= 2399);
        float4 ve;
        if (!inb) {                         // edge-pad segment: constant x
            const float xe = (g < 0) ? xb[0] : xb[TLEN - 1];
            ve = make_float4(xe, xe, xe, xe);
        }
#pragma unroll
        for (int i = 0; i < 5; ++i) {
            float4 v;
            if (inb) v = ((const float4*)(xb + 200 * g))[k + 10 * i];
            else     v = ve;
            const float c1 = c0 * C1K - sn0 * S1K, s1 = sn0 * C1K + c0 * S1K;
            const float c2 = c0 * C2K - sn0 * S2K, s2 = sn0 * C2K + c0 * S2K;
            const float c3 = c0 * C3K - sn0 * S3K, s3 = sn0 * C3K + c0 * S3K;
            p1e += v.x + v.z;             p1o += v.y + v.w;
            pce += c0 * v.x + c2 * v.z;   pco += c1 * v.y + c3 * v.w;
            pse += sn0 * v.x + s2 * v.z;  pso += s1 * v.y + s3 * v.w;
            const float cn = c0 * C40 - sn0 * S40;   // advance 40 samples
            sn0 = sn0 * C40 + c0 * S40;  c0 = cn;
        }
        part[s][k][0] = p1e;  part[s][k][1] = p1o;
        part[s][k][2] = pce;  part[s][k][3] = pco;
        part[s][k][4] = pse;  part[s][k][5] = pso;
    }
    __syncthreads();

    // fold 10 sub-partials per segment, write to global (240 floats/block)
    for (int u = threadIdx.x; u < NSEG1 * 6; u += 256) {
        const int s = u / 6;
        const int c = u - 6 * s;
        float a = 0.f;
#pragma unroll
        for (int k = 0; k < 10; ++k) a += part[s][k][c];
        pg[((size_t)b * NROWS + s0 + s) * 6 + c] = a;
    }
}

// ---------------------------------------------------------------------------
// Kernel 2: pg -> segc (Phase C, tiny) -> stream synth (Phase D).
//   x reads are L3-resident (kernel 1 just streamed all of x); write-bound.
// ---------------------------------------------------------------------------
__global__ __launch_bounds__(256) void stft_synth(const float* __restrict__ x,
                                                  const float* __restrict__ pg,
                                                  float* __restrict__ out) {
    __shared__ float  pgs[SEGO + 6][6];     // 1.1 KB: rows for g in [q0-3, q0+SEGO+2]
    __shared__ float4 segc[2][SEGO];        // 1.3 KB
    const int qb = blockIdx.x;
    const int b  = blockIdx.y;
    const int q0 = qb * SEGO;
    const float* xb = x + (size_t)b * TLEN;

    // preload pg rows: global row (q0 + local) <-> g = q0 - 3 + local
    const float* pgb = pg + ((size_t)b * NROWS + q0) * 6;
    for (int u = threadIdx.x; u < (SEGO + 6) * 6; u += 256)
        ((float*)pgs)[u] = pgb[u];
    __syncthreads();

    // Phase C: per-(segment,parity) trig constants, masked frames
    if (threadIdx.x < 2 * SEGO) {
        const int par = threadIdx.x & 1;
        const int ql  = threadIdx.x >> 1;
        const int q   = q0 + ql;
        float A = 0.f, C = 0.f, D = 0.f;
#pragma unroll
        for (int df = -1; df <= 2; ++df) {
            const int f = q + df;
            if (f < 0 || f > 2400) continue;     // boundary frame mask
            const int ls0 = f - q0 + 1;          // local index of g = f-2
            float sp1 = 0.f, spc = 0.f, sps = 0.f;
#pragma unroll
            for (int kk = 0; kk < 4; ++kk) {
                const float* rec = pgs[ls0 + kk];
                sp1 += rec[par];  spc += rec[2 + par];  sps += rec[4 + par];
            }
            const int fm = f & 3;
            const float tr = (fm == 0) ? spc : (fm == 1) ? sps : (fm == 2) ? -spc : -sps;
            const float S = 0.5f * sp1 + 0.5f * tr;
            A += S;
            if (fm == 0) C += S; else if (fm == 2) C -= S;
            else if (fm == 1) D += S; else D -= S;
        }
        segc[par][ql] = make_float4(A * (1.0f / 1600.0f),
                                    sqrtf(C * C + D * D) * (1.0f / 1600.0f),
                                    atan2f(D, C), 0.f);
    }
    __syncthreads();

    // Phase D: stream synth (x read is L3-resident; out write nontemporal)
    const bool headblk = (qb == 0);
    const bool tailblk = (qb == NT2 - 1);
    const float4* xg4 = (const float4*)(xb + HOP * q0);
    floatx4* og4 = (floatx4*)(out + (size_t)b * TLEN + HOP * q0);
    const int pmb = (q0 & 3) * 200 + 400;
    for (int j = threadIdx.x; j < 50 * SEGO; j += 256) {
        const float4 xv = xg4[j];
        const int sl = j / 50;
        const float4 ce = segc[0][sl];
        const float4 co = segc[1][sl];
        const int pm = (pmb + 4 * j) % 800;
        const float xa[4] = {xv.x, xv.y, xv.z, xv.w};
        float r[4];
#pragma unroll
        for (int c = 0; c < 4; ++c) {
            const float4 cc = (c & 1) ? co : ce;
            r[c] = 0.75f * xa[c] + cc.x - cc.y * __cosf((float)(pm + c) * DLT - cc.z);
        }
        if (headblk && sl == 0) {         // missing frame's w^2 term (analytic)
#pragma unroll
            for (int c = 0; c < 4; ++c) {
                const float wm = 0.5f + 0.5f * __sinf((float)(pm + c) * DLT);
                r[c] -= 0.5f * wm * wm * xa[c];
            }
        }
        if (tailblk && sl == SEGO - 1) {
#pragma unroll
            for (int c = 0; c < 4; ++c) {
                const float wm = 0.5f - 0.5f * __sinf((float)(pm + c) * DLT);
                r[c] -= 0.5f * wm * wm * xa[c];
            }
        }
        floatx4 rv = {r[0], r[1], r[2], r[3]};
        __builtin_nontemporal_store(rv, &og4[j]);
    }
}

// ---------------------------------------------------------------------------
// Fallback: original validated single-kernel tile (used only if d_ws is
// too small for the 1.9 MB pg staging buffer).
// ---------------------------------------------------------------------------
__global__ __launch_bounds__(256) void stft_tile(const float* __restrict__ x,
                                                 float* __restrict__ out) {
    __shared__ float  part[NSEGP][10][6];
    __shared__ float  pg[NSEGP][6];
    __shared__ float4 segc[2][SEG];

    const int qb = blockIdx.x;
    const int b  = blockIdx.y;
    const int q0 = qb * SEG;
    const float* xb = x + (size_t)b * TLEN;

    for (int u = threadIdx.x; u < NSEGP * 10; u += 256) {
        const int s = u / 10;
        const int k = u - 10 * s;
        const int g = q0 - 3 + s;
        const int gm = (g + 4) & 3;
        float c0, sn0;
        __sincosf((float)(gm * 200 + 4 * k) * DLT, &sn0, &c0);
        float p1e = 0.f, p1o = 0.f, pce = 0.f, pco = 0.f, pse = 0.f, pso = 0.f;
        const bool inb = (g >= 0) && (g <= 2399);
        float4 ve;
        if (!inb) {
            const float xe = (g < 0) ? xb[0] : xb[TLEN - 1];
            ve = make_float4(xe, xe, xe, xe);
        }
#pragma unroll
        for (int i = 0; i < 5; ++i) {
            float4 v;
            if (inb) v = ((const float4*)(xb + 200 * g))[k + 10 * i];
            else     v = ve;
            const float c1 = c0 * C1K - sn0 * S1K, s1 = sn0 * C1K + c0 * S1K;
            const float c2 = c0 * C2K - sn0 * S2K, s2 = sn0 * C2K + c0 * S2K;
            const float c3 = c0 * C3K - sn0 * S3K, s3 = sn0 * C3K + c0 * S3K;
            p1e += v.x + v.z;             p1o += v.y + v.w;
            pce += c0 * v.x + c2 * v.z;   pco += c1 * v.y + c3 * v.w;
            pse += sn0 * v.x + s2 * v.z;  pso += s1 * v.y + s3 * v.w;
            const float cn = c0 * C40 - sn0 * S40;
            sn0 = sn0 * C40 + c0 * S40;  c0 = cn;
        }
        part[s][k][0] = p1e;  part[s][k][1] = p1o;
        part[s][k][2] = pce;  part[s][k][3] = pco;
        part[s][k][4] = pse;  part[s][k][5] = pso;
    }
    __syncthreads();

    for (int u = threadIdx.x; u < NSEGP * 6; u += 256) {
        const int s = u / 6;
        const int c = u - 6 * s;
        float a = 0.f;
#pragma unroll
        for (int k = 0; k < 10; ++k) a += part[s][k][c];
        pg[s][c] = a;
    }
    __syncthreads();

    if (threadIdx.x < 2 * SEG) {
        const int par = threadIdx.x & 1;
        const int ql  = threadIdx.x >> 1;
        const int q   = q0 + ql;
        float A = 0.f, C = 0.f, D = 0.f;
#pragma unroll
        for (int df = -1; df <= 2; ++df) {
            const int f = q + df;
            if (f < 0 || f > 2400) continue;
            const int ls0 = f - q0 + 1;
            float sp1 = 0.f, spc = 0.f, sps = 0.f;
#pragma unroll
            for (int kk = 0; kk < 4; ++kk) {
                const float* rec = pg[ls0 + kk];
                sp1 += rec[par];  spc += rec[2 + par];  sps += rec[4 + par];
            }
            const int fm = f & 3;
            const float tr = (fm == 0) ? spc : (fm == 1) ? sps : (fm == 2) ? -spc : -sps;
            const float S = 0.5f * sp1 + 0.5f * tr;
            A += S;
            if (fm == 0) C += S; else if (fm == 2) C -= S;
            else if (fm == 1) D += S; else D -= S;
        }
        segc[par][ql] = make_float4(A * (1.0f / 1600.0f),
                                    sqrtf(C * C + D * D) * (1.0f / 1600.0f),
                                    atan2f(D, C), 0.f);
    }
    __syncthreads();

    const bool headblk = (qb == 0);
    const bool tailblk = (qb == NTILE - 1);
    const float4* xg4 = (const float4*)(xb + HOP * q0);
    floatx4* og4 = (floatx4*)(out + (size_t)b * TLEN + HOP * q0);
    const int pmb = (q0 & 3) * 200 + 400;
    for (int j = threadIdx.x; j < 50 * SEG; j += 256) {
        const float4 xv = xg4[j];
        const int sl = j / 50;
        const float4 ce = segc[0][sl];
        const float4 co = segc[1][sl];
        const int pm = (pmb + 4 * j) % 800;
        const float xa[4] = {xv.x, xv.y, xv.z, xv.w};
        float r[4];
#pragma unroll
        for (int c = 0; c < 4; ++c) {
            const float4 cc = (c & 1) ? co : ce;
            r[c] = 0.75f * xa[c] + cc.x - cc.y * __cosf((float)(pm + c) * DLT - cc.z);
        }
        if (headblk && sl == 0) {
#pragma unroll
            for (int c = 0; c < 4; ++c) {
                const float wm = 0.5f + 0.5f * __sinf((float)(pm + c) * DLT);
                r[c] -= 0.5f * wm * wm * xa[c];
            }
        }
        if (tailblk && sl == SEG - 1) {
#pragma unroll
            for (int c = 0; c < 4; ++c) {
                const float wm = 0.5f - 0.5f * __sinf((float)(pm + c) * DLT);
                r[c] -= 0.5f * wm * wm * xa[c];
            }
        }
        floatx4 rv = {r[0], r[1], r[2], r[3]};
        __builtin_nontemporal_store(rv, &og4[j]);
    }
}

extern "C" void kernel_launch(void* const* d_in, const int* in_sizes, int n_in,
                              void* d_out, int out_size, void* d_ws, size_t ws_size,
                              hipStream_t stream) {
    const float* x = (const float*)d_in[0];
    float* out = (float*)d_out;
    const size_t need = (size_t)NB * NROWS * 6 * sizeof(float);   // ~1.87 MB
    if (d_ws != nullptr && ws_size >= need) {
        float* pg = (float*)d_ws;
        stft_part<<<dim3(NBLK1, NB), dim3(256), 0, stream>>>(x, pg);
        stft_synth<<<dim3(NT2, NB), dim3(256), 0, stream>>>(x, pg, out);
    } else {
        stft_tile<<<dim3(NTILE, NB), dim3(256), 0, stream>>>(x, out);
    }
}

// Round 2
// 126.788 us; speedup vs baseline: 1.0092x; 1.0092x over previous
//
#include <hip/hip_runtime.h>
#include <math.h>

#define HOP     200
#define NB      32
#define TLEN    480000
#define SEG     40                     // output segments per block
#define NTILE   (TLEN / HOP / SEG)     // 60
#define NSEGP   (SEG + 6)              // 46 partial segments: [q0-3, q0+SEG+2]

#define DLT  0.00785398163397448f      // 2*pi/800
// cos/sin of k*DLT, k=1..3 (within-float4 angle stepping)
#define C1K  0.99996915760f
#define S1K  0.00785390090f
#define C2K  0.99987663248f
#define S2K  0.01570731731f
#define C3K  0.99972243010f
#define S3K  0.02355976470f
// rotation by 40*DLT = pi/10 (between a thread's successive float4s)
#define C40  0.95105651629515f
#define S40  0.30901699437495f

typedef float floatx4 __attribute__((ext_vector_type(4)));

// Analytic collapse (validated R1-R8 of prior session):
//   out[p] = 0.75*x[t] + A'(q,par) - R'(q,par)*cos(p*DLT - psi)  [+ edge w^2 corr]
// Single kernel. R2 changes vs the 41.2us/24-VGPR version:
//   * Phase A preloads all 5 float4s into v[5] BEFORE the trig chain (memory
//     ILP: 5 outstanding loads/wave instead of 1 — the 24-VGPR build
//     serialized them behind vmcnt(0)).
//   * SEG 60->40: 1920 blocks (~7.5/CU) instead of 1280 (5/CU); LDS 13.4KB.
//   * Phase D 2-unrolled: 2 independent load/compute/store per iteration.
// Math identical -> bit-identical output.
__global__ __launch_bounds__(256) void stft_tile(const float* __restrict__ x,
                                                 float* __restrict__ out) {
    __shared__ float  part[NSEGP][10][6];   // 11.0 KB
    __shared__ float  pg[NSEGP][6];         // 1.1 KB
    __shared__ float4 segc[2][SEG];         // 1.3 KB

    const int qb = blockIdx.x;              // [0, NTILE)
    const int b  = blockIdx.y;
    const int q0 = qb * SEG;
    const float* xb = x + (size_t)b * TLEN;

    // ---- Phase A: register-accumulated basis partials ----
    for (int u = threadIdx.x; u < NSEGP * 10; u += 256) {
        const int s = u / 10;
        const int k = u - 10 * s;
        const int g = q0 - 3 + s;           // [-3, 2402]
        const int gm = (g + 4) & 3;         // t mod 800 phase
        float c0, sn0;
        __sincosf((float)(gm * 200 + 4 * k) * DLT, &sn0, &c0);
        const bool inb = (g >= 0) && (g <= 2399);

        // preload ALL 5 float4s first: 5 outstanding vmem ops per lane
        float4 v[5];
        if (inb) {
            const float4* xs = (const float4*)(xb + 200 * g);
#pragma unroll
            for (int i = 0; i < 5; ++i) v[i] = xs[k + 10 * i];
        } else {                            // edge-pad segment: constant x
            const float xe = (g < 0) ? xb[0] : xb[TLEN - 1];
#pragma unroll
            for (int i = 0; i < 5; ++i) v[i] = make_float4(xe, xe, xe, xe);
        }

        float p1e = 0.f, p1o = 0.f, pce = 0.f, pco = 0.f, pse = 0.f, pso = 0.f;
#pragma unroll
        for (int i = 0; i < 5; ++i) {
            const float c1 = c0 * C1K - sn0 * S1K, s1 = sn0 * C1K + c0 * S1K;
            const float c2 = c0 * C2K - sn0 * S2K, s2 = sn0 * C2K + c0 * S2K;
            const float c3 = c0 * C3K - sn0 * S3K, s3 = sn0 * C3K + c0 * S3K;
            p1e += v[i].x + v[i].z;             p1o += v[i].y + v[i].w;
            pce += c0 * v[i].x + c2 * v[i].z;   pco += c1 * v[i].y + c3 * v[i].w;
            pse += sn0 * v[i].x + s2 * v[i].z;  pso += s1 * v[i].y + s3 * v[i].w;
            const float cn = c0 * C40 - sn0 * S40;   // advance 40 samples
            sn0 = sn0 * C40 + c0 * S40;  c0 = cn;
        }
        part[s][k][0] = p1e;  part[s][k][1] = p1o;
        part[s][k][2] = pce;  part[s][k][3] = pco;
        part[s][k][4] = pse;  part[s][k][5] = pso;
    }
    __syncthreads();

    // ---- Phase B: fold 10 sub-partials per segment ----
    for (int u = threadIdx.x; u < NSEGP * 6; u += 256) {
        const int s = u / 6;
        const int c = u - 6 * s;
        float a = 0.f;
#pragma unroll
        for (int k = 0; k < 10; ++k) a += part[s][k][c];
        pg[s][c] = a;
    }
    __syncthreads();

    // ---- Phase C: per-(segment,parity) trig constants, masked frames ----
    if (threadIdx.x < 2 * SEG) {
        const int par = threadIdx.x & 1;
        const int ql  = threadIdx.x >> 1;
        const int q   = q0 + ql;
        float A = 0.f, C = 0.f, D = 0.f;
#pragma unroll
        for (int df = -1; df <= 2; ++df) {
            const int f = q + df;
            if (f < 0 || f > 2400) continue;     // boundary frame mask
            const int ls0 = f - q0 + 1;          // local index of g=f-2
            float sp1 = 0.f, spc = 0.f, sps = 0.f;
#pragma unroll
            for (int kk = 0; kk < 4; ++kk) {
                const float* rec = pg[ls0 + kk];
                sp1 += rec[par];  spc += rec[2 + par];  sps += rec[4 + par];
            }
            const int fm = f & 3;
            const float tr = (fm == 0) ? spc : (fm == 1) ? sps : (fm == 2) ? -spc : -sps;
            const float S = 0.5f * sp1 + 0.5f * tr;
            A += S;
            if (fm == 0) C += S; else if (fm == 2) C -= S;
            else if (fm == 1) D += S; else D -= S;
        }
        segc[par][ql] = make_float4(A * (1.0f / 1600.0f),
                                    sqrtf(C * C + D * D) * (1.0f / 1600.0f),
                                    atan2f(D, C), 0.f);
    }
    __syncthreads();

    // ---- Phase D: stream synth (x re-read L2-resident from Phase A) ----
    const bool headblk = (qb == 0);
    const bool tailblk = (qb == NTILE - 1);
    const float4* xg4 = (const float4*)(xb + HOP * q0);
    floatx4* og4 = (floatx4*)(out + (size_t)b * TLEN + HOP * q0);
    const int pmb = (q0 & 3) * 200 + 400;

    auto synth1 = [&](int j, const float4& xv) -> floatx4 {
        const int sl = j / 50;
        const float4 ce = segc[0][sl];
        const float4 co = segc[1][sl];
        const int pm = (pmb + 4 * j) % 800;
        const float xa[4] = {xv.x, xv.y, xv.z, xv.w};
        float r[4];
#pragma unroll
        for (int c = 0; c < 4; ++c) {
            const float4 cc = (c & 1) ? co : ce;
            r[c] = 0.75f * xa[c] + cc.x - cc.y * __cosf((float)(pm + c) * DLT - cc.z);
        }
        if (headblk && sl == 0) {         // missing frame's w^2 term (analytic)
#pragma unroll
            for (int c = 0; c < 4; ++c) {
                const float wm = 0.5f + 0.5f * __sinf((float)(pm + c) * DLT);
                r[c] -= 0.5f * wm * wm * xa[c];
            }
        }
        if (tailblk && sl == SEG - 1) {
#pragma unroll
            for (int c = 0; c < 4; ++c) {
                const float wm = 0.5f - 0.5f * __sinf((float)(pm + c) * DLT);
                r[c] -= 0.5f * wm * wm * xa[c];
            }
        }
        floatx4 rv = {r[0], r[1], r[2], r[3]};
        return rv;
    };

    const int total = 50 * SEG;             // 2000 float4s per block
    int j = threadIdx.x;
    for (; j + 256 < total; j += 512) {
        // two independent loads issued before either compute chain
        const float4 xa = xg4[j];
        const float4 xc = xg4[j + 256];
        const floatx4 ra = synth1(j, xa);
        const floatx4 rb = synth1(j + 256, xc);
        __builtin_nontemporal_store(ra, &og4[j]);
        __builtin_nontemporal_store(rb, &og4[j + 256]);
    }
    if (j < total) {
        const float4 xa = xg4[j];
        const floatx4 ra = synth1(j, xa);
        __builtin_nontemporal_store(ra, &og4[j]);
    }
}

extern "C" void kernel_launch(void* const* d_in, const int* in_sizes, int n_in,
                              void* d_out, int out_size, void* d_ws, size_t ws_size,
                              hipStream_t stream) {
    const float* x = (const float*)d_in[0];
    float* out = (float*)d_out;
    stft_tile<<<dim3(NTILE, NB), dim3(256), 0, stream>>>(x, out);
}

// Round 3
// 120.655 us; speedup vs baseline: 1.0605x; 1.0508x over previous
//
#include <hip/hip_runtime.h>
#include <math.h>

#define HOP     200
#define NB      32
#define TLEN    480000
#define TLEN4   (TLEN / 4)
#define SEG     20                     // output segments per block
#define NTILE   (TLEN / HOP / SEG)     // 120
#define NSEGP   (SEG + 6)              // 26 partial segments: [q0-3, q0+SEG+2]
#define NW4     (50 * NSEGP)           // 1300 float4s in the x window
#define DOFF    150                    // Phase-D float4 offset into window (3 segs)

#define DLT  0.00785398163397448f      // 2*pi/800
// cos/sin of k*DLT, k=1..3 (within-float4 angle stepping)
#define C1K  0.99996915760f
#define S1K  0.00785390090f
#define C2K  0.99987663248f
#define S2K  0.01570731731f
#define C3K  0.99972243010f
#define S3K  0.02355976470f
// rotation by 40*DLT = pi/10 (between a thread's successive float4s)
#define C40  0.95105651629515f
#define S40  0.30901699437495f

typedef float floatx4 __attribute__((ext_vector_type(4)));

// Analytic collapse (validated in prior session):
//   out[p] = 0.75*x[t] + A'(q,par) - R'(q,par)*cos(p*DLT - psi)  [+ edge w^2 corr]
//
// R3 structure: LDS-resident tile. The block's raw x window is staged into
// LDS ONCE (pure coalesced stream, edge-splatted); Phases A and D both read
// x from LDS, so no global load sits on a compute critical path. Phase D's
// former L3 re-read (evicted from L2 by the aggregate Phase-A working set of
// ~160 resident blocks/XCD > 4 MiB) is gone. SEG=20 -> 28.3 KB LDS,
// 5 blocks/CU (20 waves), 3840 blocks = 3 generations so reads of gen g+1
// overlap writes of gen g. Math identical -> bit-identical output.
__global__ __launch_bounds__(256) void stft_tile(const float* __restrict__ x,
                                                 float* __restrict__ out) {
    __shared__ float4 xw4[NW4];             // 20.8 KB raw x window
    __shared__ float  part[NSEGP][10][6];   // 6.2 KB
    __shared__ float  pg[NSEGP][6];         // 0.6 KB
    __shared__ float4 segc[2][SEG];         // 0.6 KB

    const int qb = blockIdx.x;              // [0, NTILE)
    const int b  = blockIdx.y;
    const int q0 = qb * SEG;
    const float* xb = x + (size_t)b * TLEN;
    const float4* xg = (const float4*)xb;

    // ---- Phase 0: stage x window [200*(q0-3), 200*(q0+SEG+3)) into LDS ----
    {
        const int jg0 = 50 * (q0 - 3);
        float4 r[6];
#pragma unroll
        for (int i = 0; i < 6; ++i) {       // issue all loads first (ILP)
            const int j = threadIdx.x + 256 * i;
            if (j < NW4) {
                const int jg = jg0 + j;
                if (jg < 0) {                       // left edge: splat x[0]
                    const float e = xb[0];
                    r[i] = make_float4(e, e, e, e);
                } else if (jg >= TLEN4) {           // right edge: splat x[T-1]
                    const float e = xb[TLEN - 1];
                    r[i] = make_float4(e, e, e, e);
                } else {
                    r[i] = xg[jg];
                }
            }
        }
#pragma unroll
        for (int i = 0; i < 6; ++i) {
            const int j = threadIdx.x + 256 * i;
            if (j < NW4) xw4[j] = r[i];
        }
    }
    __syncthreads();

    // ---- Phase A: register-accumulated basis partials (LDS source) ----
    for (int u = threadIdx.x; u < NSEGP * 10; u += 256) {
        const int s = u / 10;
        const int k = u - 10 * s;
        const int g = q0 - 3 + s;           // [-3, 2402]
        const int gm = (g + 4) & 3;         // t mod 800 phase
        float c0, sn0;
        __sincosf((float)(gm * 200 + 4 * k) * DLT, &sn0, &c0);

        float4 v[5];
#pragma unroll
        for (int i = 0; i < 5; ++i) v[i] = xw4[50 * s + k + 10 * i];

        float p1e = 0.f, p1o = 0.f, pce = 0.f, pco = 0.f, pse = 0.f, pso = 0.f;
#pragma unroll
        for (int i = 0; i < 5; ++i) {
            const float c1 = c0 * C1K - sn0 * S1K, s1 = sn0 * C1K + c0 * S1K;
            const float c2 = c0 * C2K - sn0 * S2K, s2 = sn0 * C2K + c0 * S2K;
            const float c3 = c0 * C3K - sn0 * S3K, s3 = sn0 * C3K + c0 * S3K;
            p1e += v[i].x + v[i].z;             p1o += v[i].y + v[i].w;
            pce += c0 * v[i].x + c2 * v[i].z;   pco += c1 * v[i].y + c3 * v[i].w;
            pse += sn0 * v[i].x + s2 * v[i].z;  pso += s1 * v[i].y + s3 * v[i].w;
            const float cn = c0 * C40 - sn0 * S40;   // advance 40 samples
            sn0 = sn0 * C40 + c0 * S40;  c0 = cn;
        }
        part[s][k][0] = p1e;  part[s][k][1] = p1o;
        part[s][k][2] = pce;  part[s][k][3] = pco;
        part[s][k][4] = pse;  part[s][k][5] = pso;
    }
    __syncthreads();

    // ---- Phase B: fold 10 sub-partials per segment ----
    for (int u = threadIdx.x; u < NSEGP * 6; u += 256) {
        const int s = u / 6;
        const int c = u - 6 * s;
        float a = 0.f;
#pragma unroll
        for (int k = 0; k < 10; ++k) a += part[s][k][c];
        pg[s][c] = a;
    }
    __syncthreads();

    // ---- Phase C: per-(segment,parity) trig constants, masked frames ----
    if (threadIdx.x < 2 * SEG) {
        const int par = threadIdx.x & 1;
        const int ql  = threadIdx.x >> 1;
        const int q   = q0 + ql;
        float A = 0.f, C = 0.f, D = 0.f;
#pragma unroll
        for (int df = -1; df <= 2; ++df) {
            const int f = q + df;
            if (f < 0 || f > 2400) continue;     // boundary frame mask
            const int ls0 = f - q0 + 1;          // local index of g=f-2
            float sp1 = 0.f, spc = 0.f, sps = 0.f;
#pragma unroll
            for (int kk = 0; kk < 4; ++kk) {
                const float* rec = pg[ls0 + kk];
                sp1 += rec[par];  spc += rec[2 + par];  sps += rec[4 + par];
            }
            const int fm = f & 3;
            const float tr = (fm == 0) ? spc : (fm == 1) ? sps : (fm == 2) ? -spc : -sps;
            const float S = 0.5f * sp1 + 0.5f * tr;
            A += S;
            if (fm == 0) C += S; else if (fm == 2) C -= S;
            else if (fm == 1) D += S; else D -= S;
        }
        segc[par][ql] = make_float4(A * (1.0f / 1600.0f),
                                    sqrtf(C * C + D * D) * (1.0f / 1600.0f),
                                    atan2f(D, C), 0.f);
    }
    __syncthreads();

    // ---- Phase D: stream synth, x from LDS, nontemporal stores ----
    const bool headblk = (qb == 0);
    const bool tailblk = (qb == NTILE - 1);
    floatx4* og4 = (floatx4*)(out + (size_t)b * TLEN + HOP * q0);
    const int pmb = (q0 & 3) * 200 + 400;
    for (int j = threadIdx.x; j < 50 * SEG; j += 256) {
        const float4 xv = xw4[DOFF + j];
        const int sl = j / 50;
        const float4 ce = segc[0][sl];
        const float4 co = segc[1][sl];
        const int pm = (pmb + 4 * j) % 800;
        const float xa[4] = {xv.x, xv.y, xv.z, xv.w};
        float r[4];
#pragma unroll
        for (int c = 0; c < 4; ++c) {
            const float4 cc = (c & 1) ? co : ce;
            r[c] = 0.75f * xa[c] + cc.x - cc.y * __cosf((float)(pm + c) * DLT - cc.z);
        }
        if (headblk && sl == 0) {         // missing frame's w^2 term (analytic)
#pragma unroll
            for (int c = 0; c < 4; ++c) {
                const float wm = 0.5f + 0.5f * __sinf((float)(pm + c) * DLT);
                r[c] -= 0.5f * wm * wm * xa[c];
            }
        }
        if (tailblk && sl == SEG - 1) {
#pragma unroll
            for (int c = 0; c < 4; ++c) {
                const float wm = 0.5f - 0.5f * __sinf((float)(pm + c) * DLT);
                r[c] -= 0.5f * wm * wm * xa[c];
            }
        }
        floatx4 rv = {r[0], r[1], r[2], r[3]};
        __builtin_nontemporal_store(rv, &og4[j]);
    }
}

extern "C" void kernel_launch(void* const* d_in, const int* in_sizes, int n_in,
                              void* d_out, int out_size, void* d_ws, size_t ws_size,
                              hipStream_t stream) {
    const float* x = (const float*)d_in[0];
    float* out = (float*)d_out;
    stft_tile<<<dim3(NTILE, NB), dim3(256), 0, stream>>>(x, out);
}